// Round 6
// baseline (839.984 us; speedup 1.0000x reference)
//
#include <hip/hip_runtime.h>
#include <math.h>

#define N_NODES 50000
#define N_EDGES 800000
#define DIM_IN 64
#define DIM_HID 128
#define DIM_OUT 64
#define PAD 136    // bf16 per weight row: 272B, 16B-aligned

#define NPB  49    // nodes per bucket/block
#define NB   1021  // ceil(50000/49)
#define ACCS 68    // LDS accumulator row stride (floats); 17 float4s, spreads banks

// ws layout (bytes)
#define WS_OFF_CNT 87040    // weights: 320*PAD*2 = 87040
#define WS_OFF_LST 152576   // counts: 1021*16 ints = 65344 -> padded to 65536

typedef __attribute__((ext_vector_type(8))) short short8;   // 8 bf16 (4 VGPRs)
typedef __attribute__((ext_vector_type(4))) float f32x4;    // MFMA accumulator

union U8 { uint4 u; short8 s; };

__device__ __forceinline__ unsigned short f2bf(float f) {
    unsigned u = __float_as_uint(f);
    return (unsigned short)((u + 0x7fffu + ((u >> 16) & 1u)) >> 16);
}

__device__ __forceinline__ unsigned cvt_pk_bf16(float a, float b) {
#if __has_builtin(__builtin_amdgcn_cvt_pk_bf16_f32)
    auto pk = __builtin_amdgcn_cvt_pk_bf16_f32(a, b);   // lo=a, hi=b
    unsigned d; __builtin_memcpy(&d, &pk, 4);
    return d;
#else
    return (unsigned)f2bf(a) | ((unsigned)f2bf(b) << 16);
#endif
}

__device__ __forceinline__ float exp2_fast(float a) {
#if __has_builtin(__builtin_amdgcn_exp2f)
    return __builtin_amdgcn_exp2f(a);
#else
    return __expf(a * 0.69314718f);
#endif
}

// softplus(x) = max(x,0) + log1p(exp(-|x|)); cubic log1p fit, err ~1.5e-3
__device__ __forceinline__ unsigned sp2(float x0, float x1) {
    const float L2E = 1.44269504f;
    float z0 = exp2_fast(-fabsf(x0) * L2E);
    float z1 = exp2_fast(-fabsf(x1) * L2E);
    float p0 = fmaf(fmaf(fmaf(-0.1011458f, z0, 0.2942925f), z0, -0.5f), z0, 1.0f) * z0;
    float p1 = fmaf(fmaf(fmaf(-0.1011458f, z1, 0.2942925f), z1, -0.5f), z1, 1.0f) * z1;
    return cvt_pk_bf16(fmaxf(x0, 0.0f) + p0, fmaxf(x1, 0.0f) + p1);
}

// Weights -> bf16 W^T [n][PAD] (k-contiguous); layers 1,2 K-permuted by pi(s)
// matching the MFMA C-layout->frag register renaming.
__global__ void prep_weights(const float* __restrict__ W0,
                             const float* __restrict__ W1,
                             const float* __restrict__ W2,
                             unsigned short* __restrict__ wt) {
    int i = blockIdx.x * blockDim.x + threadIdx.x;
    if (i >= 320 * PAD) return;
    int row = i / PAD, s = i - row * PAD;
    float v = 0.f;
    if (s < 128) {
        int f = ((s >> 5) << 5) | (((s & 7) >> 2) << 4) | (((s >> 3) & 3) << 2) | (s & 3);
        if (row < 128)      v = W0[s * DIM_HID + row];
        else if (row < 256) v = W1[f * DIM_HID + (row - 128)];
        else                v = W2[f * DIM_OUT + (row - 256)];
    }
    wt[i] = f2bf(v);
}

// Pass 1: bucket edges by owner (row/NPB). Counters padded to 64B lines.
__global__ void bucket_kernel(const int* __restrict__ eidx,
                              int* __restrict__ cnts,
                              int* __restrict__ lists, int CAP) {
    int e = blockIdx.x * 256 + threadIdx.x;
    if (e >= N_EDGES) return;
    int row = eidx[e];
    int b = row / NPB;
    int slot = atomicAdd(&cnts[b * 16], 1);
    if (slot < CAP) lists[(size_t)b * CAP + slot] = e;
}

// Pass 2: owner-computes. Block b owns nodes [b*NPB, b*NPB+NPB); accumulates all
// its edges' messages in an LDS fp32 accumulator (ds_add), then writes its node
// range once with coalesced float4 stores. No global atomics anywhere.
// MLP body identical to the proven round-5 kernel (flipped L0/L1, unflipped L2).
__global__ __launch_bounds__(256, 4)
void edge_mlp_bucket(const float* __restrict__ x,
                     const int* __restrict__ eidx,
                     const unsigned short* __restrict__ wt,
                     const float* __restrict__ b0,
                     const float* __restrict__ b1,
                     const float* __restrict__ b2,
                     const int* __restrict__ cnts,
                     const int* __restrict__ lists, int CAP,
                     float* __restrict__ out) {
    __shared__ __align__(16) float acc[NPB * ACCS];

    const int tid  = threadIdx.x;
    const int base = blockIdx.x * NPB;
    const int nn   = min(NPB, N_NODES - base);

    for (int i = tid; i < NPB * ACCS; i += 256) acc[i] = 0.f;
    __syncthreads();

    const int cnt = min(cnts[blockIdx.x * 16], CAP);
    const int* lst = lists + (size_t)blockIdx.x * CAP;

    const int lane = tid & 63;
    const int w    = tid >> 6;
    const int l16  = lane & 15;
    const int q    = lane >> 4;

    const unsigned short* Wt0 = wt;
    const unsigned short* Wt1 = wt + 128 * PAD;
    const unsigned short* Wt2 = wt + 256 * PAD;

    for (int i0 = w * 32; i0 < cnt; i0 += 4 * 32) {
        // edge ids for this lane's B-frag columns (clamped; invalid guarded at scatter)
        int eI[2];
#pragma unroll
        for (int m = 0; m < 2; ++m)
            eI[m] = lst[min(i0 + m * 16 + l16, cnt - 1)];

        int nodeR[2], nodeC[2];
#pragma unroll
        for (int m = 0; m < 2; ++m) {
            nodeR[m] = eidx[eI[m]];
            nodeC[m] = eidx[N_EDGES + eI[m]];
        }

        // layer-0 B-frags straight from x
        short8 hfr[2][4];
#pragma unroll
        for (int m = 0; m < 2; ++m)
#pragma unroll
            for (int kk = 0; kk < 4; ++kk) {
                int node = (kk >= 2) ? nodeC[m] : nodeR[m];
                const float* p = x + (size_t)node * DIM_IN + (kk & 1) * 32 + q * 8;
                float4 v0 = *(const float4*)p;
                float4 v1 = *(const float4*)(p + 4);
                U8 t;
                t.u.x = cvt_pk_bf16(v0.x, v0.y);
                t.u.y = cvt_pk_bf16(v0.z, v0.w);
                t.u.z = cvt_pk_bf16(v1.x, v1.y);
                t.u.w = cvt_pk_bf16(v1.z, v1.w);
                hfr[m][kk] = t.s;
            }

        // ---- layers 0,1 (flipped): H^T = softplus(W^T H^T + b) ----
#pragma unroll
        for (int L = 0; L < 2; ++L) {
            const unsigned short* W = L ? Wt1 : Wt0;
            const float* bias = L ? b1 : b0;
            unsigned d[2][8][2];
#pragma unroll
            for (int ti = 0; ti < 8; ++ti) {
                f32x4 bb = *(const f32x4*)(bias + ti * 16 + q * 4);
                f32x4 a0 = bb, a1 = bb;
                const unsigned short* Wp = W + (ti * 16 + l16) * PAD + q * 8;
                short8 wf[4];
#pragma unroll
                for (int kk = 0; kk < 4; ++kk)
                    wf[kk] = *(const short8*)(Wp + kk * 32);
#pragma unroll
                for (int kk = 0; kk < 4; ++kk) {
                    a0 = __builtin_amdgcn_mfma_f32_16x16x32_bf16(wf[kk], hfr[0][kk], a0, 0, 0, 0);
                    a1 = __builtin_amdgcn_mfma_f32_16x16x32_bf16(wf[kk], hfr[1][kk], a1, 0, 0, 0);
                }
                d[0][ti][0] = sp2(a0[0], a0[1]);
                d[0][ti][1] = sp2(a0[2], a0[3]);
                d[1][ti][0] = sp2(a1[0], a1[1]);
                d[1][ti][1] = sp2(a1[2], a1[3]);
            }
#pragma unroll
            for (int m = 0; m < 2; ++m)
#pragma unroll
                for (int kk = 0; kk < 4; ++kk) {
                    U8 t;
                    t.u.x = d[m][2 * kk][0];
                    t.u.y = d[m][2 * kk][1];
                    t.u.z = d[m][2 * kk + 1][0];
                    t.u.w = d[m][2 * kk + 1][1];
                    hfr[m][kk] = t.s;
                }
        }

        // ---- layer 2 (un-flipped): O = H W2 + b2; C row=edge, col=feature ----
        int nl[2][4];
        bool gv[2][4];
#pragma unroll
        for (int m = 0; m < 2; ++m)
#pragma unroll
            for (int r = 0; r < 4; ++r) {
                int pos = i0 + m * 16 + q * 4 + r;
                bool v = pos < cnt;
                gv[m][r] = v;
                int e = lst[v ? pos : 0];
                nl[m][r] = v ? (eidx[e] - base) : 0;   // in [0,NPB) by bucketing
            }

#pragma unroll
        for (int ti = 0; ti < 4; ++ti) {
            float bv = b2[ti * 16 + l16];
            f32x4 a0 = (f32x4){bv, bv, bv, bv};
            f32x4 a1 = a0;
            const unsigned short* Wp = Wt2 + (ti * 16 + l16) * PAD + q * 8;
            short8 wf[4];
#pragma unroll
            for (int kk = 0; kk < 4; ++kk)
                wf[kk] = *(const short8*)(Wp + kk * 32);
#pragma unroll
            for (int kk = 0; kk < 4; ++kk) {
                a0 = __builtin_amdgcn_mfma_f32_16x16x32_bf16(hfr[0][kk], wf[kk], a0, 0, 0, 0);
                a1 = __builtin_amdgcn_mfma_f32_16x16x32_bf16(hfr[1][kk], wf[kk], a1, 0, 0, 0);
            }
#pragma unroll
            for (int r = 0; r < 4; ++r) {
                if (gv[0][r]) atomicAdd(&acc[nl[0][r] * ACCS + ti * 16 + l16], a0[r]);
                if (gv[1][r]) atomicAdd(&acc[nl[1][r] * ACCS + ti * 16 + l16], a1[r]);
            }
        }
    }

    __syncthreads();
    // write this block's node range (exclusive ownership -> plain stores)
    const float4* accv = (const float4*)acc;
    float4* outv = (float4*)out;
    for (int i = tid; i < nn * 16; i += 256) {
        int nlw = i >> 4, fq = i & 15;
        outv[(size_t)(base + nlw) * 16 + fq] = accv[nlw * 17 + fq];
    }
}

// ---------------- fallback (round-5 proven path, global atomics) ----------------
__global__ __launch_bounds__(256, 4)
void edge_mlp_atomic(const float* __restrict__ x,
                     const int* __restrict__ eidx,
                     const unsigned short* __restrict__ wt,
                     const float* __restrict__ b0,
                     const float* __restrict__ b1,
                     const float* __restrict__ b2,
                     float* __restrict__ out) {
    const int lane = threadIdx.x & 63;
    const int w    = threadIdx.x >> 6;
    const int l16  = lane & 15;
    const int q    = lane >> 4;
    const int e0w  = blockIdx.x * 128 + w * 32;

    const unsigned short* Wt0 = wt;
    const unsigned short* Wt1 = wt + 128 * PAD;
    const unsigned short* Wt2 = wt + 256 * PAD;

    int nodeR[2], nodeC[2];
#pragma unroll
    for (int m = 0; m < 2; ++m) {
        nodeR[m] = eidx[e0w + m * 16 + l16];
        nodeC[m] = eidx[N_EDGES + e0w + m * 16 + l16];
    }

    short8 hfr[2][4];
#pragma unroll
    for (int m = 0; m < 2; ++m)
#pragma unroll
        for (int kk = 0; kk < 4; ++kk) {
            int node = (kk >= 2) ? nodeC[m] : nodeR[m];
            const float* p = x + (size_t)node * DIM_IN + (kk & 1) * 32 + q * 8;
            float4 v0 = *(const float4*)p;
            float4 v1 = *(const float4*)(p + 4);
            U8 t;
            t.u.x = cvt_pk_bf16(v0.x, v0.y);
            t.u.y = cvt_pk_bf16(v0.z, v0.w);
            t.u.z = cvt_pk_bf16(v1.x, v1.y);
            t.u.w = cvt_pk_bf16(v1.z, v1.w);
            hfr[m][kk] = t.s;
        }

#pragma unroll
    for (int L = 0; L < 2; ++L) {
        const unsigned short* W = L ? Wt1 : Wt0;
        const float* bias = L ? b1 : b0;
        unsigned d[2][8][2];
#pragma unroll
        for (int ti = 0; ti < 8; ++ti) {
            f32x4 bb = *(const f32x4*)(bias + ti * 16 + q * 4);
            f32x4 a0 = bb, a1 = bb;
            const unsigned short* Wp = W + (ti * 16 + l16) * PAD + q * 8;
            short8 wf[4];
#pragma unroll
            for (int kk = 0; kk < 4; ++kk)
                wf[kk] = *(const short8*)(Wp + kk * 32);
#pragma unroll
            for (int kk = 0; kk < 4; ++kk) {
                a0 = __builtin_amdgcn_mfma_f32_16x16x32_bf16(wf[kk], hfr[0][kk], a0, 0, 0, 0);
                a1 = __builtin_amdgcn_mfma_f32_16x16x32_bf16(wf[kk], hfr[1][kk], a1, 0, 0, 0);
            }
            d[0][ti][0] = sp2(a0[0], a0[1]);
            d[0][ti][1] = sp2(a0[2], a0[3]);
            d[1][ti][0] = sp2(a1[0], a1[1]);
            d[1][ti][1] = sp2(a1[2], a1[3]);
        }
#pragma unroll
        for (int m = 0; m < 2; ++m)
#pragma unroll
            for (int kk = 0; kk < 4; ++kk) {
                U8 t;
                t.u.x = d[m][2 * kk][0];
                t.u.y = d[m][2 * kk][1];
                t.u.z = d[m][2 * kk + 1][0];
                t.u.w = d[m][2 * kk + 1][1];
                hfr[m][kk] = t.s;
            }
    }

    int nodeO[2][4];
#pragma unroll
    for (int m = 0; m < 2; ++m)
#pragma unroll
        for (int r = 0; r < 4; ++r)
            nodeO[m][r] = eidx[e0w + m * 16 + q * 4 + r];

#pragma unroll
    for (int ti = 0; ti < 4; ++ti) {
        float bv = b2[ti * 16 + l16];
        f32x4 a0 = (f32x4){bv, bv, bv, bv};
        f32x4 a1 = a0;
        const unsigned short* Wp = Wt2 + (ti * 16 + l16) * PAD + q * 8;
        short8 wf[4];
#pragma unroll
        for (int kk = 0; kk < 4; ++kk)
            wf[kk] = *(const short8*)(Wp + kk * 32);
#pragma unroll
        for (int kk = 0; kk < 4; ++kk) {
            a0 = __builtin_amdgcn_mfma_f32_16x16x32_bf16(hfr[0][kk], wf[kk], a0, 0, 0, 0);
            a1 = __builtin_amdgcn_mfma_f32_16x16x32_bf16(hfr[1][kk], wf[kk], a1, 0, 0, 0);
        }
#pragma unroll
        for (int r = 0; r < 4; ++r) {
            atomicAdd(out + (size_t)nodeO[0][r] * DIM_OUT + ti * 16 + l16, a0[r]);
            atomicAdd(out + (size_t)nodeO[1][r] * DIM_OUT + ti * 16 + l16, a1[r]);
        }
    }
}

extern "C" void kernel_launch(void* const* d_in, const int* in_sizes, int n_in,
                              void* d_out, int out_size, void* d_ws, size_t ws_size,
                              hipStream_t stream) {
    const float* x  = (const float*)d_in[0];
    const int*   ei = (const int*)d_in[1];
    const float* W0 = (const float*)d_in[2];
    const float* b0 = (const float*)d_in[3];
    const float* W1 = (const float*)d_in[4];
    const float* b1 = (const float*)d_in[5];
    const float* W2 = (const float*)d_in[6];
    const float* b2 = (const float*)d_in[7];
    float* out = (float*)d_out;

    unsigned short* wt = (unsigned short*)d_ws;
    int* cnts  = (int*)((char*)d_ws + WS_OFF_CNT);
    int* lists = (int*)((char*)d_ws + WS_OFF_LST);

    const int wn = 320 * PAD;
    prep_weights<<<(wn + 255) / 256, 256, 0, stream>>>(W0, W1, W2, wt);

    // capacity per bucket from available scratch (mean fill ~784)
    long avail = (long)ws_size - (long)WS_OFF_LST;
    int CAP = (avail > 0) ? (int)(avail / ((long)NB * 4)) : 0;
    if (CAP > 3072) CAP = 3072;

    if (CAP >= 1280) {
        hipMemsetAsync(cnts, 0, NB * 16 * sizeof(int), stream);
        bucket_kernel<<<(N_EDGES + 255) / 256, 256, 0, stream>>>(ei, cnts, lists, CAP);
        edge_mlp_bucket<<<NB, 256, 0, stream>>>(x, ei, wt, b0, b1, b2,
                                                cnts, lists, CAP, out);
    } else {
        hipMemsetAsync(out, 0, (size_t)N_NODES * DIM_OUT * sizeof(float), stream);
        edge_mlp_atomic<<<N_EDGES / 128, 256, 0, stream>>>(x, ei, wt, b0, b1, b2, out);
    }
}

// Round 7
// 374.475 us; speedup vs baseline: 2.2431x; 2.2431x over previous
//
#include <hip/hip_runtime.h>
#include <math.h>

#define N_NODES 50000
#define N_EDGES 800000
#define DIM_IN 64
#define DIM_HID 128
#define DIM_OUT 64
#define PAD 136    // bf16 per weight row: 272B, 16B-aligned

#define NPAD 50176  // 196*256, padded node count for scan

// ws layout (bytes)
#define WS_WT    0
#define WS_CNT   87040                    // 50176 ints
#define WS_PREF  (WS_CNT + 200704)
#define WS_BSUM  (WS_PREF + 200704)
#define WS_BSCAN (WS_BSUM + 1024)
#define WS_CUR   (WS_BSCAN + 1024)
#define WS_EP    (WS_CUR + 200704)
#define WS_NEED  (WS_EP + 3200000)        // ~3.89 MB

typedef __attribute__((ext_vector_type(8))) short short8;   // 8 bf16 (4 VGPRs)
typedef __attribute__((ext_vector_type(4))) float f32x4;    // MFMA accumulator

union U8 { uint4 u; short8 s; };

__device__ __forceinline__ unsigned short f2bf(float f) {
    unsigned u = __float_as_uint(f);
    return (unsigned short)((u + 0x7fffu + ((u >> 16) & 1u)) >> 16);
}

__device__ __forceinline__ unsigned cvt_pk_bf16(float a, float b) {
#if __has_builtin(__builtin_amdgcn_cvt_pk_bf16_f32)
    auto pk = __builtin_amdgcn_cvt_pk_bf16_f32(a, b);   // lo=a, hi=b
    unsigned d; __builtin_memcpy(&d, &pk, 4);
    return d;
#else
    return (unsigned)f2bf(a) | ((unsigned)f2bf(b) << 16);
#endif
}

__device__ __forceinline__ float exp2_fast(float a) {
#if __has_builtin(__builtin_amdgcn_exp2f)
    return __builtin_amdgcn_exp2f(a);
#else
    return __expf(a * 0.69314718f);
#endif
}

// softplus(x) = max(x,0) + log1p(exp(-|x|)); cubic log1p fit, err ~1.5e-3
__device__ __forceinline__ unsigned sp2(float x0, float x1) {
    const float L2E = 1.44269504f;
    float z0 = exp2_fast(-fabsf(x0) * L2E);
    float z1 = exp2_fast(-fabsf(x1) * L2E);
    float p0 = fmaf(fmaf(fmaf(-0.1011458f, z0, 0.2942925f), z0, -0.5f), z0, 1.0f) * z0;
    float p1 = fmaf(fmaf(fmaf(-0.1011458f, z1, 0.2942925f), z1, -0.5f), z1, 1.0f) * z1;
    return cvt_pk_bf16(fmaxf(x0, 0.0f) + p0, fmaxf(x1, 0.0f) + p1);
}

// Weights -> bf16 W^T [n][PAD] (k-contiguous); layers 1,2 K-permuted by pi(s)
// matching the MFMA C-layout->frag register renaming (proven rounds 4-5).
__global__ void prep_weights(const float* __restrict__ W0,
                             const float* __restrict__ W1,
                             const float* __restrict__ W2,
                             unsigned short* __restrict__ wt) {
    int i = blockIdx.x * blockDim.x + threadIdx.x;
    if (i >= 320 * PAD) return;
    int row = i / PAD, s = i - row * PAD;
    float v = 0.f;
    if (s < 128) {
        int f = ((s >> 5) << 5) | (((s & 7) >> 2) << 4) | (((s >> 3) & 3) << 2) | (s & 3);
        if (row < 128)      v = W0[s * DIM_HID + row];
        else if (row < 256) v = W1[f * DIM_HID + (row - 128)];
        else                v = W2[f * DIM_OUT + (row - 256)];
    }
    wt[i] = f2bf(v);
}

// ---------- counting sort of edges by destination (row) node ----------
__global__ void hist_kernel(const int* __restrict__ eidx, int* __restrict__ cnt) {
    int e = blockIdx.x * 256 + threadIdx.x;
    if (e < N_EDGES) atomicAdd(&cnt[eidx[e]], 1);
}

// per-256-block exclusive scan (Hillis-Steele in LDS); bsum = block totals
__global__ void scan1_kernel(const int* __restrict__ cnt,
                             int* __restrict__ pref, int* __restrict__ bsum) {
    __shared__ int s[256];
    int t = threadIdx.x, i = blockIdx.x * 256 + t;
    int v = (i < N_NODES) ? cnt[i] : 0;
    s[t] = v;
    __syncthreads();
#pragma unroll
    for (int d = 1; d < 256; d <<= 1) {
        int add = (t >= d) ? s[t - d] : 0;
        __syncthreads();
        s[t] += add;
        __syncthreads();
    }
    pref[i] = s[t] - v;                     // exclusive within block
    if (t == 255) bsum[blockIdx.x] = s[255];
}

__global__ void scan2_kernel(int* __restrict__ bsum, int* __restrict__ bscan) {
    __shared__ int s[256];
    int t = threadIdx.x;
    int v = (t < 196) ? bsum[t] : 0;
    s[t] = v;
    __syncthreads();
#pragma unroll
    for (int d = 1; d < 256; d <<= 1) {
        int add = (t >= d) ? s[t - d] : 0;
        __syncthreads();
        s[t] += add;
        __syncthreads();
    }
    bscan[t] = s[t] - v;
}

__global__ void scan3_kernel(const int* __restrict__ pref,
                             const int* __restrict__ bscan,
                             int* __restrict__ cur) {
    int i = blockIdx.x * 256 + threadIdx.x;
    cur[i] = pref[i] + bscan[blockIdx.x];
}

// scatter packed (row | col<<16) into sorted-by-row order
__global__ void scatter_pairs(const int* __restrict__ eidx, int* __restrict__ cur,
                              unsigned* __restrict__ ep) {
    int e = blockIdx.x * 256 + threadIdx.x;
    if (e >= N_EDGES) return;
    int row = eidx[e];
    int col = eidx[N_EDGES + e];
    int slot = atomicAdd(&cur[row], 1);
    ep[slot] = (unsigned)row | ((unsigned)col << 16);
}

// ---------- main MLP kernel (round-5 proven body, sorted-edge input) ----------
// Layers 0,1 flipped: mfma(A=weight, B=activation); C col=l16=edge, row=feature;
// inter-layer transform = softplus + cvt_pk + register renaming (pi in weights).
// Layer 2 un-flipped: C row=q*4+r=edge (4 consecutive sorted edges in one lane's
// f32x4!), col=feature -> per-lane merge of same-node runs before atomicAdd.
__global__ __launch_bounds__(256, 4)
void edge_mlp_sorted(const float* __restrict__ x,
                     const unsigned* __restrict__ ep,
                     const unsigned short* __restrict__ wt,
                     const float* __restrict__ b0,
                     const float* __restrict__ b1,
                     const float* __restrict__ b2,
                     float* __restrict__ out) {
    const int lane = threadIdx.x & 63;
    const int w    = threadIdx.x >> 6;
    const int l16  = lane & 15;
    const int q    = lane >> 4;
    const int e0w  = blockIdx.x * 128 + w * 32;   // this wave's 32 sorted edges

    const unsigned short* Wt0 = wt;
    const unsigned short* Wt1 = wt + 128 * PAD;
    const unsigned short* Wt2 = wt + 256 * PAD;

    int nodeR[2], nodeC[2];
#pragma unroll
    for (int m = 0; m < 2; ++m) {
        unsigned pr = ep[e0w + m * 16 + l16];
        nodeR[m] = (int)(pr & 0xFFFFu);
        nodeC[m] = (int)(pr >> 16);
    }

    // layer-0 B-frags straight from x (row side is run-clustered -> L1-hot)
    short8 hfr[2][4];
#pragma unroll
    for (int m = 0; m < 2; ++m)
#pragma unroll
        for (int kk = 0; kk < 4; ++kk) {
            int node = (kk >= 2) ? nodeC[m] : nodeR[m];
            const float* p = x + (size_t)node * DIM_IN + (kk & 1) * 32 + q * 8;
            float4 v0 = *(const float4*)p;
            float4 v1 = *(const float4*)(p + 4);
            U8 t;
            t.u.x = cvt_pk_bf16(v0.x, v0.y);
            t.u.y = cvt_pk_bf16(v0.z, v0.w);
            t.u.z = cvt_pk_bf16(v1.x, v1.y);
            t.u.w = cvt_pk_bf16(v1.z, v1.w);
            hfr[m][kk] = t.s;
        }

    // ---- layers 0,1 (flipped): H^T = softplus(W^T H^T + b) ----
#pragma unroll
    for (int L = 0; L < 2; ++L) {
        const unsigned short* W = L ? Wt1 : Wt0;
        const float* bias = L ? b1 : b0;
        unsigned d[2][8][2];
#pragma unroll
        for (int ti = 0; ti < 8; ++ti) {
            f32x4 bb = *(const f32x4*)(bias + ti * 16 + q * 4);
            f32x4 a0 = bb, a1 = bb;
            const unsigned short* Wp = W + (ti * 16 + l16) * PAD + q * 8;
            short8 wf[4];
#pragma unroll
            for (int kk = 0; kk < 4; ++kk)
                wf[kk] = *(const short8*)(Wp + kk * 32);
#pragma unroll
            for (int kk = 0; kk < 4; ++kk) {
                a0 = __builtin_amdgcn_mfma_f32_16x16x32_bf16(wf[kk], hfr[0][kk], a0, 0, 0, 0);
                a1 = __builtin_amdgcn_mfma_f32_16x16x32_bf16(wf[kk], hfr[1][kk], a1, 0, 0, 0);
            }
            d[0][ti][0] = sp2(a0[0], a0[1]);
            d[0][ti][1] = sp2(a0[2], a0[3]);
            d[1][ti][0] = sp2(a1[0], a1[1]);
            d[1][ti][1] = sp2(a1[2], a1[3]);
        }
#pragma unroll
        for (int m = 0; m < 2; ++m)
#pragma unroll
            for (int kk = 0; kk < 4; ++kk) {
                U8 t;
                t.u.x = d[m][2 * kk][0];
                t.u.y = d[m][2 * kk][1];
                t.u.z = d[m][2 * kk + 1][0];
                t.u.w = d[m][2 * kk + 1][1];
                hfr[m][kk] = t.s;
            }
    }

    // ---- layer 2 (un-flipped): O = H W2 + b2; per-lane run merge + atomics ----
    int nO[2][4];
#pragma unroll
    for (int m = 0; m < 2; ++m) {
        uint4 po = *(const uint4*)(ep + e0w + m * 16 + q * 4);  // 4 consecutive edges
        nO[m][0] = (int)(po.x & 0xFFFFu);
        nO[m][1] = (int)(po.y & 0xFFFFu);
        nO[m][2] = (int)(po.z & 0xFFFFu);
        nO[m][3] = (int)(po.w & 0xFFFFu);
    }

#pragma unroll
    for (int ti = 0; ti < 4; ++ti) {
        float bv = b2[ti * 16 + l16];
        f32x4 a0 = (f32x4){bv, bv, bv, bv};
        f32x4 a1 = a0;
        const unsigned short* Wp = Wt2 + (ti * 16 + l16) * PAD + q * 8;
        short8 wf[4];
#pragma unroll
        for (int kk = 0; kk < 4; ++kk)
            wf[kk] = *(const short8*)(Wp + kk * 32);
#pragma unroll
        for (int kk = 0; kk < 4; ++kk) {
            a0 = __builtin_amdgcn_mfma_f32_16x16x32_bf16(hfr[0][kk], wf[kk], a0, 0, 0, 0);
            a1 = __builtin_amdgcn_mfma_f32_16x16x32_bf16(hfr[1][kk], wf[kk], a1, 0, 0, 0);
        }
        const int c = ti * 16 + l16;
#pragma unroll
        for (int m = 0; m < 2; ++m) {
            const f32x4& a = m ? a1 : a0;
            int n0 = nO[m][0], n1 = nO[m][1], n2 = nO[m][2], n3 = nO[m][3];
            float s01 = a[0] + a[1], s23 = a[2] + a[3];
            if (n0 == n3 && n0 == n1 && n2 == n3) {
                atomicAdd(out + (size_t)n0 * DIM_OUT + c, s01 + s23);
            } else {
                if (n0 == n1) atomicAdd(out + (size_t)n0 * DIM_OUT + c, s01);
                else {
                    atomicAdd(out + (size_t)n0 * DIM_OUT + c, a[0]);
                    atomicAdd(out + (size_t)n1 * DIM_OUT + c, a[1]);
                }
                if (n2 == n3) atomicAdd(out + (size_t)n2 * DIM_OUT + c, s23);
                else {
                    atomicAdd(out + (size_t)n2 * DIM_OUT + c, a[2]);
                    atomicAdd(out + (size_t)n3 * DIM_OUT + c, a[3]);
                }
            }
        }
    }
}

// ---------------- fallback (round-5 proven path, unsorted atomics) ----------------
__global__ __launch_bounds__(256, 4)
void edge_mlp_atomic(const float* __restrict__ x,
                     const int* __restrict__ eidx,
                     const unsigned short* __restrict__ wt,
                     const float* __restrict__ b0,
                     const float* __restrict__ b1,
                     const float* __restrict__ b2,
                     float* __restrict__ out) {
    const int lane = threadIdx.x & 63;
    const int w    = threadIdx.x >> 6;
    const int l16  = lane & 15;
    const int q    = lane >> 4;
    const int e0w  = blockIdx.x * 128 + w * 32;

    const unsigned short* Wt0 = wt;
    const unsigned short* Wt1 = wt + 128 * PAD;
    const unsigned short* Wt2 = wt + 256 * PAD;

    int nodeR[2], nodeC[2];
#pragma unroll
    for (int m = 0; m < 2; ++m) {
        nodeR[m] = eidx[e0w + m * 16 + l16];
        nodeC[m] = eidx[N_EDGES + e0w + m * 16 + l16];
    }

    short8 hfr[2][4];
#pragma unroll
    for (int m = 0; m < 2; ++m)
#pragma unroll
        for (int kk = 0; kk < 4; ++kk) {
            int node = (kk >= 2) ? nodeC[m] : nodeR[m];
            const float* p = x + (size_t)node * DIM_IN + (kk & 1) * 32 + q * 8;
            float4 v0 = *(const float4*)p;
            float4 v1 = *(const float4*)(p + 4);
            U8 t;
            t.u.x = cvt_pk_bf16(v0.x, v0.y);
            t.u.y = cvt_pk_bf16(v0.z, v0.w);
            t.u.z = cvt_pk_bf16(v1.x, v1.y);
            t.u.w = cvt_pk_bf16(v1.z, v1.w);
            hfr[m][kk] = t.s;
        }

#pragma unroll
    for (int L = 0; L < 2; ++L) {
        const unsigned short* W = L ? Wt1 : Wt0;
        const float* bias = L ? b1 : b0;
        unsigned d[2][8][2];
#pragma unroll
        for (int ti = 0; ti < 8; ++ti) {
            f32x4 bb = *(const f32x4*)(bias + ti * 16 + q * 4);
            f32x4 a0 = bb, a1 = bb;
            const unsigned short* Wp = W + (ti * 16 + l16) * PAD + q * 8;
            short8 wf[4];
#pragma unroll
            for (int kk = 0; kk < 4; ++kk)
                wf[kk] = *(const short8*)(Wp + kk * 32);
#pragma unroll
            for (int kk = 0; kk < 4; ++kk) {
                a0 = __builtin_amdgcn_mfma_f32_16x16x32_bf16(wf[kk], hfr[0][kk], a0, 0, 0, 0);
                a1 = __builtin_amdgcn_mfma_f32_16x16x32_bf16(wf[kk], hfr[1][kk], a1, 0, 0, 0);
            }
            d[0][ti][0] = sp2(a0[0], a0[1]);
            d[0][ti][1] = sp2(a0[2], a0[3]);
            d[1][ti][0] = sp2(a1[0], a1[1]);
            d[1][ti][1] = sp2(a1[2], a1[3]);
        }
#pragma unroll
        for (int m = 0; m < 2; ++m)
#pragma unroll
            for (int kk = 0; kk < 4; ++kk) {
                U8 t;
                t.u.x = d[m][2 * kk][0];
                t.u.y = d[m][2 * kk][1];
                t.u.z = d[m][2 * kk + 1][0];
                t.u.w = d[m][2 * kk + 1][1];
                hfr[m][kk] = t.s;
            }
    }

    int nodeO[2][4];
#pragma unroll
    for (int m = 0; m < 2; ++m)
#pragma unroll
        for (int r = 0; r < 4; ++r)
            nodeO[m][r] = eidx[e0w + m * 16 + q * 4 + r];

#pragma unroll
    for (int ti = 0; ti < 4; ++ti) {
        float bv = b2[ti * 16 + l16];
        f32x4 a0 = (f32x4){bv, bv, bv, bv};
        f32x4 a1 = a0;
        const unsigned short* Wp = Wt2 + (ti * 16 + l16) * PAD + q * 8;
        short8 wf[4];
#pragma unroll
        for (int kk = 0; kk < 4; ++kk)
            wf[kk] = *(const short8*)(Wp + kk * 32);
#pragma unroll
        for (int kk = 0; kk < 4; ++kk) {
            a0 = __builtin_amdgcn_mfma_f32_16x16x32_bf16(hfr[0][kk], wf[kk], a0, 0, 0, 0);
            a1 = __builtin_amdgcn_mfma_f32_16x16x32_bf16(hfr[1][kk], wf[kk], a1, 0, 0, 0);
        }
#pragma unroll
        for (int r = 0; r < 4; ++r) {
            atomicAdd(out + (size_t)nodeO[0][r] * DIM_OUT + ti * 16 + l16, a0[r]);
            atomicAdd(out + (size_t)nodeO[1][r] * DIM_OUT + ti * 16 + l16, a1[r]);
        }
    }
}

extern "C" void kernel_launch(void* const* d_in, const int* in_sizes, int n_in,
                              void* d_out, int out_size, void* d_ws, size_t ws_size,
                              hipStream_t stream) {
    const float* x  = (const float*)d_in[0];
    const int*   ei = (const int*)d_in[1];
    const float* W0 = (const float*)d_in[2];
    const float* b0 = (const float*)d_in[3];
    const float* W1 = (const float*)d_in[4];
    const float* b1 = (const float*)d_in[5];
    const float* W2 = (const float*)d_in[6];
    const float* b2 = (const float*)d_in[7];
    float* out = (float*)d_out;

    char* ws = (char*)d_ws;
    unsigned short* wt = (unsigned short*)(ws + WS_WT);
    int* cnt   = (int*)(ws + WS_CNT);
    int* pref  = (int*)(ws + WS_PREF);
    int* bsum  = (int*)(ws + WS_BSUM);
    int* bscan = (int*)(ws + WS_BSCAN);
    int* cur   = (int*)(ws + WS_CUR);
    unsigned* ep = (unsigned*)(ws + WS_EP);

    const int wn = 320 * PAD;
    prep_weights<<<(wn + 255) / 256, 256, 0, stream>>>(W0, W1, W2, wt);

    hipMemsetAsync(out, 0, (size_t)N_NODES * DIM_OUT * sizeof(float), stream);

    if (ws_size >= (size_t)WS_NEED) {
        hipMemsetAsync(cnt, 0, NPAD * sizeof(int), stream);
        hist_kernel<<<(N_EDGES + 255) / 256, 256, 0, stream>>>(ei, cnt);
        scan1_kernel<<<NPAD / 256, 256, 0, stream>>>(cnt, pref, bsum);
        scan2_kernel<<<1, 256, 0, stream>>>(bsum, bscan);
        scan3_kernel<<<NPAD / 256, 256, 0, stream>>>(pref, bscan, cur);
        scatter_pairs<<<(N_EDGES + 255) / 256, 256, 0, stream>>>(ei, cur, ep);
        edge_mlp_sorted<<<N_EDGES / 128, 256, 0, stream>>>(x, ep, wt, b0, b1, b2, out);
    } else {
        edge_mlp_atomic<<<N_EDGES / 128, 256, 0, stream>>>(x, ei, wt, b0, b1, b2, out);
    }
}